// Round 1
// baseline (9168.778 us; speedup 1.0000x reference)
//
#include <hip/hip_runtime.h>
#include <stdint.h>

// ---- types ----
typedef __attribute__((ext_vector_type(8))) short short8;   // 8 bf16 = 4 VGPR (MFMA A/B frag)
typedef __attribute__((ext_vector_type(4))) short short4v;  // 4 bf16 = 8B
typedef __attribute__((ext_vector_type(4))) float f32x4;    // MFMA C/D frag
typedef __attribute__((ext_vector_type(4))) unsigned int u32x4;

// ---- bf16 helpers (manual RNE; avoids __hip_bfloat16 ABI differences) ----
__device__ inline unsigned short f2bf(float f) {
  unsigned int u = __builtin_bit_cast(unsigned int, f);
  u += 0x7fffu + ((u >> 16) & 1u);
  return (unsigned short)(u >> 16);
}
__device__ inline float bf2f(unsigned short s) {
  return __builtin_bit_cast(float, (unsigned int)s << 16);
}

// Problem constants: B=32, T=512, D=H=1024, 4H=4096, M = T*B = 16384
// gx layout: [t][n][b] bf16 where n = permuted gate-row (4*j + gate), b = batch
// hs layout: [t][b][j]  bf16, flat row m = t*32+b  (doubles as GEMM B-operand rows)

// ---- x: [B][T][D] f32  ->  xbf: [m = t*32+b][d] bf16 ----
__global__ __launch_bounds__(256) void cvt_x_kernel(const float* __restrict__ x,
                                                    short* __restrict__ xbf) {
  const int total = (16384 * 1024) / 4;
  for (int i = blockIdx.x * blockDim.x + threadIdx.x; i < total;
       i += gridDim.x * blockDim.x) {
    int d4 = i & 255;      // float4 index within row of 1024
    int m  = i >> 8;       // 0..16383, m = t*32 + b
    int t = m >> 5, b = m & 31;
    float4 v = *(const float4*)(x + ((size_t)b * 512 + t) * 1024 + (size_t)d4 * 4);
    short4v o;
    o.x = (short)f2bf(v.x); o.y = (short)f2bf(v.y);
    o.z = (short)f2bf(v.z); o.w = (short)f2bf(v.w);
    *(short4v*)(xbf + (size_t)m * 1024 + d4 * 4) = o;
  }
}

// ---- W: [4096][1024] f32 -> Wp: gate-interleaved rows, bf16.
// new row n = 4*j + g  <-  old row g*1024 + j   (g in {i,f,g,o}) ----
__global__ __launch_bounds__(256) void cvt_w_kernel(const float* __restrict__ W,
                                                    short* __restrict__ Wp) {
  const int total = (4096 * 1024) / 4;
  for (int i = blockIdx.x * blockDim.x + threadIdx.x; i < total;
       i += gridDim.x * blockDim.x) {
    int k4 = i & 255;
    int n  = i >> 8;
    int g = n & 3, j = n >> 2;
    float4 v = *(const float4*)(W + ((size_t)g * 1024 + j) * 1024 + (size_t)k4 * 4);
    short4v o;
    o.x = (short)f2bf(v.x); o.y = (short)f2bf(v.y);
    o.z = (short)f2bf(v.z); o.w = (short)f2bf(v.w);
    *(short4v*)(Wp + (size_t)n * 1024 + k4 * 4) = o;
  }
}

// ---- bias permute (stays f32) ----
__global__ __launch_bounds__(256) void cvt_b_kernel(const float* __restrict__ b,
                                                    float* __restrict__ bp) {
  int n = blockIdx.x * blockDim.x + threadIdx.x;
  if (n < 4096) bp[n] = b[(n & 3) * 1024 + (n >> 2)];
}

// ---- bf16 MFMA GEMM:  C[n][m] = sum_k A[n][k] * Bm[m][k]
// A = Wp [4096][1024], Bm = xbf/hs0 [16384][1024], C = gx [t][n][b] bf16.
// 128x128 tile, BK=32, 4 waves in 2x2, each wave 4x4 of 16x16x32 MFMA. ----
__global__ __launch_bounds__(256) void gemm_bt(const short* __restrict__ A,
                                               const short* __restrict__ Bm,
                                               short* __restrict__ C) {
  const int n0 = blockIdx.x * 128;   // gate-row tile
  const int m0 = blockIdx.y * 128;   // (t,b) tile
  const int tid = threadIdx.x;
  const int lane = tid & 63, wid = tid >> 6;
  const int wr = wid >> 1, wc = wid & 1;
  const int fr = lane & 15, fq = lane >> 4;

  __shared__ __align__(16) short As[128 * 32];
  __shared__ __align__(16) short Bs[128 * 32];

  f32x4 acc[4][4];
#pragma unroll
  for (int i = 0; i < 4; i++)
#pragma unroll
    for (int j = 0; j < 4; j++) acc[i][j] = (f32x4){0.f, 0.f, 0.f, 0.f};

  for (int kt = 0; kt < 1024; kt += 32) {
    // stage 8KB A-tile + 8KB B-tile: 512 chunks of 16B each, 256 threads x 2
#pragma unroll
    for (int s = 0; s < 2; s++) {
      int c = tid + s * 256;
      int row = c >> 2;
      int off = (c & 3) * 8;  // in shorts (16B)
      *(u32x4*)&As[row * 32 + off] =
          *(const u32x4*)(A + (size_t)(n0 + row) * 1024 + kt + off);
      *(u32x4*)&Bs[row * 32 + off] =
          *(const u32x4*)(Bm + (size_t)(m0 + row) * 1024 + kt + off);
    }
    __syncthreads();
    short8 af[4], bf[4];
#pragma unroll
    for (int i = 0; i < 4; i++)
      af[i] = *(const short8*)&As[(wr * 64 + i * 16 + fr) * 32 + fq * 8];
#pragma unroll
    for (int j = 0; j < 4; j++)
      bf[j] = *(const short8*)&Bs[(wc * 64 + j * 16 + fr) * 32 + fq * 8];
#pragma unroll
    for (int i = 0; i < 4; i++)
#pragma unroll
      for (int j = 0; j < 4; j++)
        acc[i][j] = __builtin_amdgcn_mfma_f32_16x16x32_bf16(af[i], bf[j], acc[i][j], 0, 0, 0);
    __syncthreads();
  }

  // epilogue: D row = n = (lane>>4)*4 + r within 16-tile, col = m = lane&15
#pragma unroll
  for (int i = 0; i < 4; i++) {
#pragma unroll
    for (int j = 0; j < 4; j++) {
#pragma unroll
      for (int r = 0; r < 4; r++) {
        int n = n0 + wr * 64 + i * 16 + fq * 4 + r;
        int m = m0 + wc * 64 + j * 16 + fr;
        int t = m >> 5, b = m & 31;
        C[(size_t)t * 131072 + (size_t)n * 32 + b] = (short)f2bf(acc[i][j][r]);
      }
    }
  }
}

// ---- one LSTM timestep. 256 WGs x 128 thr (2 waves).
// WG owns 16 permuted gate-rows (= 4 h-cols). wave wid covers batches wid*16..+15.
// gates[n][b] = gx[t][n][b] + bias[n] + sum_k Whh_p[n][k] * h[t-1][b][k]
// D layout => lane (q=lane>>4, fr=lane&15): regs r=0..3 = i,f,g,o of
// h-col j = wg*4+q, batch b = wid*16+fr. Cell update fully lane-local. ----
__global__ __launch_bounds__(128) void lstm_step(
    int t, const short* __restrict__ gx, const short* __restrict__ Whh,
    const float* __restrict__ bias, short* __restrict__ hs,
    float* __restrict__ c_buf, float* __restrict__ out,
    float* __restrict__ hn, float* __restrict__ cn) {
  const int wg = blockIdx.x;        // 0..255
  const int n_base = wg * 16;
  const int lane = threadIdx.x & 63, wid = threadIdx.x >> 6;
  const int fr = lane & 15, q = lane >> 4;
  const int b = wid * 16 + fr;

  f32x4 acc = (f32x4){0.f, 0.f, 0.f, 0.f};
  if (t > 0) {
    const short* hp = hs + (size_t)(t - 1) * 32768;           // [b][j]
    const short* arow = Whh + (size_t)(n_base + fr) * 1024 + q * 8;
    const short* brow = hp + (size_t)b * 1024 + q * 8;
#pragma unroll 4
    for (int k = 0; k < 1024; k += 32) {
      short8 a  = *(const short8*)(arow + k);
      short8 h8 = *(const short8*)(brow + k);
      acc = __builtin_amdgcn_mfma_f32_16x16x32_bf16(a, h8, acc, 0, 0, 0);
    }
  }

  const short* gxt = gx + (size_t)t * 131072;
  float pre[4];
#pragma unroll
  for (int r = 0; r < 4; r++) {
    int n = n_base + q * 4 + r;
    pre[r] = acc[r] + bf2f((unsigned short)gxt[n * 32 + b]) + bias[n];
  }
  float iv = 1.f / (1.f + __expf(-pre[0]));
  float fv = 1.f / (1.f + __expf(-pre[1]));
  float gv = 2.f / (1.f + __expf(-2.f * pre[2])) - 1.f;
  float ov = 1.f / (1.f + __expf(-pre[3]));

  int j = wg * 4 + q;
  float c_old = (t > 0) ? c_buf[b * 1024 + j] : 0.f;
  float c_new = fv * c_old + iv * gv;
  c_buf[b * 1024 + j] = c_new;
  float h = ov * (2.f / (1.f + __expf(-2.f * c_new)) - 1.f);

  hs[(size_t)t * 32768 + (size_t)b * 1024 + j] = (short)f2bf(h);
  if (out) out[(size_t)b * 524288 + (size_t)t * 1024 + j] = h;  // [B][T][H]
  if (t == 511) {
    hn[b * 1024 + j] = h;
    cn[b * 1024 + j] = c_new;
  }
}

extern "C" void kernel_launch(void* const* d_in, const int* in_sizes, int n_in,
                              void* d_out, int out_size, void* d_ws, size_t ws_size,
                              hipStream_t stream) {
  const float* x    = (const float*)d_in[0];
  const float* Wih0 = (const float*)d_in[1];
  const float* b0   = (const float*)d_in[2];
  const float* Whh0 = (const float*)d_in[3];
  const float* Wih1 = (const float*)d_in[4];
  const float* b1   = (const float*)d_in[5];
  const float* Whh1 = (const float*)d_in[6];

  float* out = (float*)d_out;          // [32][512][1024]
  float* hn  = out + 16777216;         // [2][32][1024]
  float* cn  = hn + 65536;             // [2][32][1024]

  // workspace carve (~224 MB)
  char* ws = (char*)d_ws;
  size_t off = 0;
  auto carve = [&](size_t bytes) {
    char* p = ws + off;
    off += (bytes + 255) & ~(size_t)255;
    return p;
  };
  short* xbf   = (short*)carve(16384ull * 1024 * 2);  // reused as hs1 later
  short* wih0p = (short*)carve(4096ull * 1024 * 2);
  short* whh0p = (short*)carve(4096ull * 1024 * 2);
  short* wih1p = (short*)carve(4096ull * 1024 * 2);
  short* whh1p = (short*)carve(4096ull * 1024 * 2);
  float* b0p   = (float*)carve(4096 * 4);
  float* b1p   = (float*)carve(4096 * 4);
  float* c_buf = (float*)carve(32 * 1024 * 4);
  short* gx    = (short*)carve(512ull * 4096 * 32 * 2);  // [t][n][b], reused by layer 1
  short* hs0   = (short*)carve(16384ull * 1024 * 2);

  // phase 0: conversions / permutations
  hipLaunchKernelGGL(cvt_x_kernel, dim3(4096), dim3(256), 0, stream, x, xbf);
  hipLaunchKernelGGL(cvt_w_kernel, dim3(1024), dim3(256), 0, stream, Wih0, wih0p);
  hipLaunchKernelGGL(cvt_w_kernel, dim3(1024), dim3(256), 0, stream, Whh0, whh0p);
  hipLaunchKernelGGL(cvt_w_kernel, dim3(1024), dim3(256), 0, stream, Wih1, wih1p);
  hipLaunchKernelGGL(cvt_w_kernel, dim3(1024), dim3(256), 0, stream, Whh1, whh1p);
  hipLaunchKernelGGL(cvt_b_kernel, dim3(16), dim3(256), 0, stream, b0, b0p);
  hipLaunchKernelGGL(cvt_b_kernel, dim3(16), dim3(256), 0, stream, b1, b1p);

  // layer 0
  hipLaunchKernelGGL(gemm_bt, dim3(32, 128), dim3(256), 0, stream, wih0p, xbf, gx);
  for (int t = 0; t < 512; t++)
    hipLaunchKernelGGL(lstm_step, dim3(256), dim3(128), 0, stream,
                       t, (const short*)gx, (const short*)whh0p, (const float*)b0p,
                       hs0, c_buf, (float*)nullptr, hn, cn);

  // layer 1 (hs1 reuses xbf storage; c_buf reused, t==0 doesn't read it)
  hipLaunchKernelGGL(gemm_bt, dim3(32, 128), dim3(256), 0, stream, wih1p, hs0, gx);
  short* hs1 = xbf;
  for (int t = 0; t < 512; t++)
    hipLaunchKernelGGL(lstm_step, dim3(256), dim3(128), 0, stream,
                       t, (const short*)gx, (const short*)whh1p, (const float*)b1p,
                       hs1, c_buf, out, hn + 32768, cn + 32768);
}